// Round 12
// baseline (342.974 us; speedup 1.0000x reference)
//
#include <hip/hip_runtime.h>
#include <hip/hip_bf16.h>

// Attention: xq/xk/xv [2,2048,768] f32, W* [768,768] f32 ([out,in]), bp [768] f32.
// Pipeline: fused cast->bf16, fused QKV NT-GEMM (r17: 128x96 tiles, 768 blocks,
// 2-phase overlap + setprio), flash attention SPLIT-KV (r19): 1536 blocks =
// 6/CU (2 blocks per (bh,qt), each 64q x 1024kv, 32-kv tiles, 16.75 KB LDS,
// launch_bounds(256,6) for 24 waves/CU TLP; 32x32 MFMA, in-register P via
// cvt_pk+permlane, overlap schedule). Blocks write UN-NORMALIZED f32 partial
// O + l (max-free softmax => partials combine exactly); a small combine kernel
// computes (P0+P1)/(l0+l1) -> ctx bf16. Partials live in dead buffers:
// P0=out(f32), P1=Xq+Xk, L=Xv. Output NT-GEMM + bias (r17: 64x96, 512 blocks,
// overlap + setprio). LDS XOR-swizzled everywhere.

#define NSEQ 2048
#define CDIM 768
#define NH   12
#define HD   64
#define MTOT 4096            // B*NSEQ
#define XEL  (MTOT*CDIM)     // 3145728
#define WEL  (CDIM*CDIM)     // 589824
#define X8   (XEL/8)         // 393216
#define W8   (WEL/8)         // 73728
#define QSCALE 0.18033688011112042f   // 0.125 * log2(e); scores consumed by exp2

typedef __attribute__((ext_vector_type(8))) short bf16x8;
typedef __attribute__((ext_vector_type(4))) float floatx4;
typedef __attribute__((ext_vector_type(16))) float floatx16;
typedef __attribute__((ext_vector_type(4))) unsigned int uintx4;

// scalar f32->bf16, round-half-up (2 VALU)
static __device__ __forceinline__ unsigned short f2bf(float f) {
  union { float f; unsigned int u; } v; v.f = f;
  return (unsigned short)((v.u + 0x8000u) >> 16);
}
// packed pair f32->bf16x2, round-half-up: 2 v_add + 1 v_perm
static __device__ __forceinline__ unsigned pk2bf(float a, float b) {
  unsigned ua = __float_as_uint(a) + 0x8000u;
  unsigned ub = __float_as_uint(b) + 0x8000u;
  return __builtin_amdgcn_perm(ub, ua, 0x07060302);  // {hi16(b), hi16(a)}
}
// packed pair f32->bf16x2 via HW cvt (1 VALU, RNE): dst = {bf16(a), bf16(b)}
static __device__ __forceinline__ unsigned cvtpk(float a, float b) {
  unsigned r;
  asm("v_cvt_pk_bf16_f32 %0, %1, %2" : "=v"(r) : "v"(a), "v"(b));
  return r;
}

static __device__ __forceinline__ void lds16(const void* g, void* l) {
  __builtin_amdgcn_global_load_lds(
      (const __attribute__((address_space(1))) unsigned int*)g,
      (__attribute__((address_space(3))) unsigned int*)l, 16, 0, 0);
}

// fences for the overlap schedules
#define LGKM0_SB()  do { asm volatile("s_waitcnt lgkmcnt(0)" ::: "memory"); \
                         __builtin_amdgcn_sched_barrier(0); } while (0)
#define VMCNT0()    asm volatile("s_waitcnt vmcnt(0)" ::: "memory")
#define BARRIER()   __builtin_amdgcn_s_barrier()
#define SB0()       __builtin_amdgcn_sched_barrier(0)
#define PRIO1()     __builtin_amdgcn_s_setprio(1)
#define PRIO0()     __builtin_amdgcn_s_setprio(0)

// ---------------- fused cast f32 -> bf16 (all 7 tensors, one launch) ----------
__global__ __launch_bounds__(256) void cast_all(
    const float* __restrict__ xq, const float* __restrict__ xk,
    const float* __restrict__ xv, const float* __restrict__ wq,
    const float* __restrict__ wk, const float* __restrict__ wv,
    const float* __restrict__ wp,
    unsigned short* __restrict__ Xq, unsigned short* __restrict__ Xk,
    unsigned short* __restrict__ Xv, unsigned short* __restrict__ Wq,
    unsigned short* __restrict__ Wk, unsigned short* __restrict__ Wv,
    unsigned short* __restrict__ Wp) {
  int i = blockIdx.x * 256 + threadIdx.x;
  const float* s; unsigned short* d; int off;
  if (i < 3 * X8) {
    int t = i / X8; off = i - t * X8;
    s = (t == 0) ? xq : (t == 1) ? xk : xv;
    d = (t == 0) ? Xq : (t == 1) ? Xk : Xv;
  } else {
    int j = i - 3 * X8; int t = j / W8; off = j - t * W8;
    s = (t == 0) ? wq : (t == 1) ? wk : (t == 2) ? wv : wp;
    d = (t == 0) ? Wq : (t == 1) ? Wk : (t == 2) ? Wv : Wp;
  }
  const float4* sp = (const float4*)s + (size_t)off * 2;
  float4 a = sp[0], b = sp[1];
  uint4 o;
  o.x = pk2bf(a.x, a.y); o.y = pk2bf(a.z, a.w);
  o.z = pk2bf(b.x, b.y); o.w = pk2bf(b.z, b.w);
  *(uint4*)(d + (size_t)off * 8) = o;
}

// ---------------- fused QKV NT-GEMM: r17 version (768 blocks, 3/CU) ---------
__global__ __launch_bounds__(256) void gemm_qkv(
    const unsigned short* __restrict__ Xq, const unsigned short* __restrict__ Xk,
    const unsigned short* __restrict__ Xv, const unsigned short* __restrict__ Wq,
    const unsigned short* __restrict__ Wk, const unsigned short* __restrict__ Wv,
    unsigned short* __restrict__ Qo, unsigned short* __restrict__ Ko,
    unsigned short* __restrict__ Vo) {
  int i0 = blockIdx.x;
  int mg = i0 & 7; int t0 = i0 >> 3;       // t0 in [0,96)
  int z = t0 % 3; int u = t0 / 3;          // u in [0,32)
  int xn = u & 7, ysub = u >> 3;           // 8 n-tiles x 4 m-subtiles
  int y = mg * 4 + ysub;                   // m-tile in [0,32)
  const unsigned short* A; const unsigned short* B; int am0, bn0, RA;
  if (z == 0)      { A = Xq; B = Wq; am0 = y * 128; bn0 = xn * 96; RA = 128; }
  else if (z == 1) { A = Xk; B = Wk; am0 = y * 128; bn0 = xn * 96; RA = 128; }
  else             { A = Wv; B = Xv; am0 = xn * 96; bn0 = y * 128; RA = 96; }
  __shared__ __align__(16) unsigned short S[224 * 64];
  int tid = threadIdx.x, lane = tid & 63, wave = tid >> 6;
  int quad = lane >> 4, l15 = lane & 15, l7 = l15 & 7;

  const unsigned short* gptr[7]; int ldo[7];
#pragma unroll
  for (int i = 0; i < 7; i++) {
    int idx = i * 256 + tid;
    int row = idx >> 3, c = (idx & 7) ^ (row & 7);
    gptr[i] = (row < RA ? A + (size_t)(am0 + row) * CDIM
                        : B + (size_t)(bn0 + row - RA) * CDIM) + c * 8;
    ldo[i] = idx * 8;
  }
  floatx4 acc[12];
#pragma unroll
  for (int i = 0; i < 12; i++) acc[i] = (floatx4){0.f, 0.f, 0.f, 0.f};

  // prologue: stage k0=0
#pragma unroll
  for (int i = 0; i < 7; i++) lds16(gptr[i], &S[ldo[i]]);
  VMCNT0();
  BARRIER();

  if (z < 2) {
    int wm = (wave >> 1) * 64, wn = (wave & 1) * 48;
    for (int k0 = 0; k0 < CDIM; k0 += 64) {
      bf16x8 af[2][4], bfr[2][3];
#pragma unroll
      for (int ks = 0; ks < 2; ks++) {
        int csw = ((ks * 4 + quad) ^ l7) * 8;
#pragma unroll
        for (int i = 0; i < 4; i++)
          af[ks][i] = *(const bf16x8*)&S[(wm + i * 16 + l15) * 64 + csw];
#pragma unroll
        for (int j = 0; j < 3; j++)
          bfr[ks][j] = *(const bf16x8*)&S[(128 + wn + j * 16 + l15) * 64 + csw];
      }
      LGKM0_SB();
      BARRIER();
      if (k0 + 64 < CDIM) {
#pragma unroll
        for (int i = 0; i < 7; i++) lds16(gptr[i] + k0 + 64, &S[ldo[i]]);
      }
      SB0();
      PRIO1();
#pragma unroll
      for (int ks = 0; ks < 2; ks++)
#pragma unroll
        for (int mi = 0; mi < 4; mi++)
#pragma unroll
          for (int ni = 0; ni < 3; ni++)
            acc[mi * 3 + ni] = __builtin_amdgcn_mfma_f32_16x16x32_bf16(
                af[ks][mi], bfr[ks][ni], acc[mi * 3 + ni], 0, 0, 0);
      PRIO0();
      VMCNT0();
      BARRIER();
    }
#pragma unroll
    for (int mi = 0; mi < 4; mi++)
#pragma unroll
      for (int ni = 0; ni < 3; ni++)
#pragma unroll
        for (int r = 0; r < 4; r++) {
          int grow = am0 + wm + mi * 16 + quad * 4 + r;
          int gcol = bn0 + wn + ni * 16 + l15;
          float v = acc[mi * 3 + ni][r];
          int b = grow >> 11, nq = grow & 2047, h = gcol >> 6, dd = gcol & 63;
          if (z == 0)
            Qo[((size_t)(b * NH + h) * NSEQ + nq) * HD + dd] = f2bf(v * QSCALE);
          else
            Ko[((size_t)(b * NH + h) * NSEQ + nq) * HD + dd] = f2bf(v);
        }
  } else {
    int wm = (wave & 1) * 48, wn = (wave >> 1) * 64;
    for (int k0 = 0; k0 < CDIM; k0 += 64) {
      bf16x8 af[2][3], bfr[2][4];
#pragma unroll
      for (int ks = 0; ks < 2; ks++) {
        int csw = ((ks * 4 + quad) ^ l7) * 8;
#pragma unroll
        for (int i = 0; i < 3; i++)
          af[ks][i] = *(const bf16x8*)&S[(wm + i * 16 + l15) * 64 + csw];
#pragma unroll
        for (int j = 0; j < 4; j++)
          bfr[ks][j] = *(const bf16x8*)&S[(96 + wn + j * 16 + l15) * 64 + csw];
      }
      LGKM0_SB();
      BARRIER();
      if (k0 + 64 < CDIM) {
#pragma unroll
        for (int i = 0; i < 7; i++) lds16(gptr[i] + k0 + 64, &S[ldo[i]]);
      }
      SB0();
      PRIO1();
#pragma unroll
      for (int ks = 0; ks < 2; ks++)
#pragma unroll
        for (int mi = 0; mi < 3; mi++)
#pragma unroll
          for (int ni = 0; ni < 4; ni++)
            acc[mi * 4 + ni] = __builtin_amdgcn_mfma_f32_16x16x32_bf16(
                af[ks][mi], bfr[ks][ni], acc[mi * 4 + ni], 0, 0, 0);
      PRIO0();
      VMCNT0();
      BARRIER();
    }
#pragma unroll
    for (int mi = 0; mi < 3; mi++)
#pragma unroll
      for (int ni = 0; ni < 4; ni++)
#pragma unroll
        for (int r = 0; r < 4; r++) {
          int o = am0 + wm + mi * 16 + quad * 4 + r;
          int mgl = bn0 + wn + ni * 16 + l15;
          int b = mgl >> 11, nq = mgl & 2047;
          Vo[((size_t)b * CDIM + o) * NSEQ + nq] = f2bf(acc[mi * 4 + ni][r]);
        }
  }
}

// ---------------- flash attention r19: split-kv partials ---------------------
// Q,K: [24][2048][64] bf16 (Q pre-scaled); Vt: [24][64][2048] bf16.
// 1536 blocks (6/CU) x 256 thr = 4 waves: block = (bh, qt, kvh) covers
// 64 q x 1024 kv. wave = (half<<1)|qsub: 32 q x 512 kv per wave, 16 tiles of
// 32 kv. LDS: one 16 KB arena (K halves 0-8KB, V halves 8-16KB) + Lbuf ->
// 16.75 KB -> 6 blocks/CU with launch_bounds(256,6) (VGPR<=85).
// Per tile: 8 frag ds_read -> lgkm0+schedbar+barrier -> stage t+1 same buffer
// -> register compute (4 QK MFMA chain, 16 exp2, 8 cvt_pk, permlane, 4 PV) ->
// vmcnt0+barrier. Max-free softmax: block writes UN-NORMALIZED partial
// O (f32, [slot][64q][64d]) + l; cross-block combine is exact.
__global__ __launch_bounds__(256, 6) void attn_part(
    const unsigned short* __restrict__ Q, const unsigned short* __restrict__ K,
    const unsigned short* __restrict__ Vt,
    float* __restrict__ P0, float* __restrict__ P1,
    float* __restrict__ L0, float* __restrict__ L1) {
  int i0 = blockIdx.x;
  int xcd = i0 & 7; int t0 = i0 >> 3;      // [0,192)
  int bh = xcd * 3 + (t0 >> 6);
  int rem = t0 & 63;
  int qt = rem >> 1, kvh = rem & 1;
  int tid = threadIdx.x, lane = tid & 63, wave = tid >> 6;
  int half = wave >> 1, qsub = wave & 1;
  int l31 = lane & 31, hi = lane >> 5;
  // SM arena: [0,8KB) = K halves (2 x 32x64 bf16), [8KB,16KB) = V halves
  __shared__ __align__(16) unsigned short SM[8192];
  __shared__ float Lbuf[64];

  const unsigned short* Qg = Q + ((size_t)bh * NSEQ + qt * 64 + qsub * 32) * HD;
  const unsigned short* Kg = K + ((size_t)bh * NSEQ + kvh * 1024 + half * 512) * HD;
  const unsigned short* Vg = Vt + (size_t)bh * HD * NSEQ + kvh * 1024 + half * 512;

  // Q fragments (B-operand): lane holds Q[q=l31][d = dc*16 + hi*8 + j]
  bf16x8 qf[4];
#pragma unroll
  for (int dc = 0; dc < 4; dc++)
    qf[dc] = *(const bf16x8*)(Qg + l31 * HD + dc * 16 + hi * 8);

  // staging: each half's 128 threads stage 4KB K (32x64) + 4KB V (64x32)
  int tid2 = tid & 127;
  int kgo[2], kst[2], vgo[2], vst[2];
#pragma unroll
  for (int i = 0; i < 2; i++) {
    int idx = i * 128 + tid2;
    int Rk = idx >> 3, ck = (idx & 7) ^ (Rk & 7);
    kgo[i] = Rk * HD + ck * 8; kst[i] = idx * 8;
    int Rv = idx >> 2, cv = (idx & 3) ^ (Rv & 3);
    vgo[i] = Rv * NSEQ + cv * 8; vst[i] = idx * 8;
  }
  unsigned short* Ksh = &SM[half * 2048];
  unsigned short* Vsh = &SM[4096 + half * 2048];

  floatx16 o[2];
#pragma unroll
  for (int dt = 0; dt < 2; dt++) o[dt] = (floatx16)(0.f);
  float l_acc = 0.f;

  // prologue: stage tile 0
#pragma unroll
  for (int i = 0; i < 2; i++) {
    lds16(Kg + kgo[i], &Ksh[kst[i]]);
    lds16(Vg + vgo[i], &Vsh[vst[i]]);
  }
  VMCNT0();
  BARRIER();

  for (int t = 0; t < 16; t++) {
    // (a) fragment reads of tile t (32 kv)
    bf16x8 kf[4];
#pragma unroll
    for (int dc = 0; dc < 4; dc++) {
      int c = dc * 2 + hi;
      kf[dc] = *(const bf16x8*)&Ksh[l31 * 64 + ((c ^ (l31 & 7)) * 8)];
    }
    bf16x8 vf[2][2];
#pragma unroll
    for (int dt = 0; dt < 2; dt++)
#pragma unroll
      for (int kvs = 0; kvs < 2; kvs++) {
        int R = dt * 32 + l31, c = kvs * 2 + hi;
        vf[dt][kvs] = *(const bf16x8*)&Vsh[R * 32 + ((c ^ (R & 3)) * 8)];
      }
    // (b) readers-done fence
    LGKM0_SB();
    BARRIER();
    // (c) stage tile t+1 into the same buffer
    if (t < 15) {
      int off = (t + 1) * 32;
#pragma unroll
      for (int i = 0; i < 2; i++) {
        lds16(Kg + (size_t)off * HD + kgo[i], &Ksh[kst[i]]);
        lds16(Vg + off + vgo[i], &Vsh[vst[i]]);
      }
    }
    SB0();
    // (d) register-only compute: S^T[kv32][q32] = K Q^T
    floatx16 st = (floatx16)(0.f);
    PRIO1();
#pragma unroll
    for (int dc = 0; dc < 4; dc++)
      st = __builtin_amdgcn_mfma_f32_32x32x16_bf16(kf[dc], qf[dc], st, 0, 0, 0);
    PRIO0();
    float p[16];
#pragma unroll
    for (int r = 0; r < 16; r++) p[r] = __builtin_exp2f(st[r]);
    l_acc += ((p[0] + p[1]) + (p[2] + p[3])) + ((p[4] + p[5]) + (p[6] + p[7])) +
             (((p[8] + p[9]) + (p[10] + p[11])) + ((p[12] + p[13]) + (p[14] + p[15])));
    unsigned w[8];
#pragma unroll
    for (int i = 0; i < 8; i++) w[i] = cvtpk(p[2 * i], p[2 * i + 1]);
#pragma unroll
    for (int kvs = 0; kvs < 2; kvs++) {
      unsigned a0 = w[kvs * 4 + 0], b0 = w[kvs * 4 + 2];
      unsigned a1 = w[kvs * 4 + 1], b1 = w[kvs * 4 + 3];
      asm volatile("v_permlane32_swap_b32 %0, %1" : "+v"(a0), "+v"(b0));
      asm volatile("v_permlane32_swap_b32 %0, %1" : "+v"(a1), "+v"(b1));
      uintx4 pw; pw[0] = a0; pw[1] = a1; pw[2] = b0; pw[3] = b1;
      bf16x8 pb = *(bf16x8*)&pw;
      PRIO1();
#pragma unroll
      for (int dt = 0; dt < 2; dt++)
        o[dt] = __builtin_amdgcn_mfma_f32_32x32x16_bf16(
            vf[dt][kvs], pb, o[dt], 0, 0, 0);
      PRIO0();
    }
    // (e) stage-done fence
    VMCNT0();
    BARRIER();
  }

  // complete l across lane halves
  unsigned lu = __float_as_uint(l_acc), lv = __float_as_uint(l_acc);
  asm volatile("v_permlane32_swap_b32 %0, %1" : "+v"(lu), "+v"(lv));
  float lfull = __uint_as_float(lu) + __uint_as_float(lv);

  // in-block kv-half combine: half-1 -> LDS (SM arena, 16 KB Obuf), half-0
  // adds and writes UN-NORMALIZED partial + l to global.
  float* Obuf = (float*)&SM[0];   // 64q x 64d f32 = 16 KB
  int q = qsub * 32 + l31;
  int slot = bh * 32 + qt;
  float* Pdst = (kvh == 0) ? P0 : P1;
  float* Ldst = (kvh == 0) ? L0 : L1;
  if (half == 1) {
#pragma unroll
    for (int dt = 0; dt < 2; dt++)
#pragma unroll
      for (int rq = 0; rq < 4; rq++) {
        int ch = (dt * 8 + rq * 2 + hi) ^ (l31 & 15);
        floatx4 v4 = {o[dt][rq * 4 + 0], o[dt][rq * 4 + 1],
                      o[dt][rq * 4 + 2], o[dt][rq * 4 + 3]};
        *(floatx4*)&Obuf[q * 64 + ch * 4] = v4;
      }
    if (hi == 0) Lbuf[q] = lfull;
  }
  __syncthreads();
  if (half == 0) {
#pragma unroll
    for (int dt = 0; dt < 2; dt++)
#pragma unroll
      for (int rq = 0; rq < 4; rq++) {
        int ch = (dt * 8 + rq * 2 + hi) ^ (l31 & 15);
        floatx4 ob = *(floatx4*)&Obuf[q * 64 + ch * 4];
        floatx4 v4 = {o[dt][rq * 4 + 0] + ob[0], o[dt][rq * 4 + 1] + ob[1],
                      o[dt][rq * 4 + 2] + ob[2], o[dt][rq * 4 + 3] + ob[3]};
        *(floatx4*)&Pdst[(size_t)slot * 4096 + q * 64 + dt * 32 + rq * 8 + hi * 4] = v4;
      }
    if (hi == 0) Ldst[slot * 64 + q] = lfull + Lbuf[q];
  }
}

// ---------------- attn combine: ctx = (P0+P1) / (l0+l1) ----------------------
// 768 blocks x 256 thr; each block = one (bh,qt) slot. Thread handles 16
// contiguous f32 (one q row, 16 d's) -> 16 bf16 (32B coalesced store).
__global__ __launch_bounds__(256) void attn_combine(
    const float* __restrict__ P0, const float* __restrict__ P1,
    const float* __restrict__ L0, const float* __restrict__ L1,
    unsigned short* __restrict__ ctx) {
  int slot = blockIdx.x;
  int bh = slot >> 5, qt = slot & 31;
  int b = bh / NH, h = bh - b * NH;
  int tid = threadIdx.x;
  int e0 = tid * 16;
  int q = e0 >> 6, d0 = e0 & 63;
  float inv = 1.f / (L0[slot * 64 + q] + L1[slot * 64 + q]);
  const float4* p0 = (const float4*)(P0 + (size_t)slot * 4096 + e0);
  const float4* p1 = (const float4*)(P1 + (size_t)slot * 4096 + e0);
  unsigned short* dst =
      ctx + ((size_t)(b * NSEQ + qt * 64 + q)) * CDIM + h * HD + d0;
#pragma unroll
  for (int g = 0; g < 2; g++) {
    float4 x0 = p0[g * 2 + 0], x1 = p0[g * 2 + 1];
    float4 y0 = p1[g * 2 + 0], y1 = p1[g * 2 + 1];
    uint4 ov;
    ov.x = pk2bf((x0.x + y0.x) * inv, (x0.y + y0.y) * inv);
    ov.y = pk2bf((x0.z + y0.z) * inv, (x0.w + y0.w) * inv);
    ov.z = pk2bf((x1.x + y1.x) * inv, (x1.y + y1.y) * inv);
    ov.w = pk2bf((x1.z + y1.z) * inv, (x1.w + y1.w) * inv);
    *(uint4*)(dst + g * 8) = ov;
  }
}

// ------------- output NT-GEMM + bias, 64x96 tiles, BK=128, XCD-swizzled ------
// 2-phase overlap schedule + T5 setprio (r17 version, 512 blocks).
__global__ __launch_bounds__(256) void gemm_out(
    const unsigned short* __restrict__ A, const unsigned short* __restrict__ B,
    const float* __restrict__ bias, float* __restrict__ out) {
  int i0 = blockIdx.x;                  // 512 blocks = 2/CU
  int mg = i0 & 7; int t0 = i0 >> 3;    // t0 in [0,64)
  int n0 = (t0 & 7) * 96;
  int m0 = (mg * 8 + (t0 >> 3)) * 64;
  __shared__ __align__(16) unsigned short S[160 * 128];  // A rows 0..63, B rows 64..159
  int tid = threadIdx.x, lane = tid & 63, wave = tid >> 6;
  int quad = lane >> 4, l15 = lane & 15, l7 = l15 & 7;
  int wm = (wave >> 1) * 32, wn = (wave & 1) * 48;
  floatx4 acc[6];
#pragma unroll
  for (int i = 0; i < 6; i++) acc[i] = (floatx4){0.f, 0.f, 0.f, 0.f};

  int sro[10]; const unsigned short* sgp[10];
#pragma unroll
  for (int i = 0; i < 10; i++) {       // 160 rows x 16 chunks = 2560 = 10*256
    int idx = i * 256 + tid;
    int R = idx >> 4, c4 = idx & 15;
    int cs = (c4 & 8) | ((c4 & 7) ^ (R & 7));
    sgp[i] = ((R < 64) ? A + (size_t)(m0 + R) * CDIM
                       : B + (size_t)(n0 + R - 64) * CDIM) + cs * 8;
    sro[i] = idx * 8;
  }
  // prologue: stage k0=0
#pragma unroll
  for (int i = 0; i < 10; i++) lds16(sgp[i], &S[sro[i]]);
  VMCNT0();
  BARRIER();

  for (int k0 = 0; k0 < CDIM; k0 += 128) {
    bf16x8 af[4][2], bfr[4][3];
#pragma unroll
    for (int ks = 0; ks < 4; ks++) {
      int c = ks * 4 + quad;
      int csw = ((c & 8) | ((c & 7) ^ l7)) * 8;
#pragma unroll
      for (int i = 0; i < 2; i++)
        af[ks][i] = *(const bf16x8*)&S[(wm + i * 16 + l15) * 128 + csw];
#pragma unroll
      for (int j = 0; j < 3; j++)
        bfr[ks][j] = *(const bf16x8*)&S[(64 + wn + j * 16 + l15) * 128 + csw];
    }
    LGKM0_SB();
    BARRIER();
    if (k0 + 128 < CDIM) {
#pragma unroll
      for (int i = 0; i < 10; i++) lds16(sgp[i] + k0 + 128, &S[sro[i]]);
    }
    SB0();
    PRIO1();
#pragma unroll
    for (int ks = 0; ks < 4; ks++)
#pragma unroll
      for (int mi = 0; mi < 2; mi++)
#pragma unroll
        for (int ni = 0; ni < 3; ni++)
          acc[mi * 3 + ni] = __builtin_amdgcn_mfma_f32_16x16x32_bf16(
              af[ks][mi], bfr[ks][ni], acc[mi * 3 + ni], 0, 0, 0);
    PRIO0();
    VMCNT0();
    BARRIER();
  }
  float bv[3];
#pragma unroll
  for (int ni = 0; ni < 3; ni++) bv[ni] = bias[n0 + wn + ni * 16 + l15];
#pragma unroll
  for (int mi = 0; mi < 2; mi++)
#pragma unroll
    for (int ni = 0; ni < 3; ni++)
#pragma unroll
      for (int r = 0; r < 4; r++) {
        int grow = m0 + wm + mi * 16 + quad * 4 + r;
        int gcol = n0 + wn + ni * 16 + l15;
        out[(size_t)grow * CDIM + gcol] = acc[mi * 3 + ni][r] + bv[ni];
      }
}

extern "C" void kernel_launch(void* const* d_in, const int* in_sizes, int n_in,
                              void* d_out, int out_size, void* d_ws, size_t ws_size,
                              hipStream_t stream) {
  const float* xq = (const float*)d_in[0];
  const float* xk = (const float*)d_in[1];
  const float* xv = (const float*)d_in[2];
  const float* wq = (const float*)d_in[3];
  const float* wk = (const float*)d_in[4];
  const float* wv = (const float*)d_in[5];
  const float* wp = (const float*)d_in[6];
  const float* bp = (const float*)d_in[7];
  float* out = (float*)d_out;

  char* p = (char*)d_ws;
  unsigned short* Xq = (unsigned short*)p; p += (size_t)XEL * 2;
  unsigned short* Xk = (unsigned short*)p; p += (size_t)XEL * 2;
  unsigned short* Xv = (unsigned short*)p; p += (size_t)XEL * 2;
  unsigned short* Wq = (unsigned short*)p; p += (size_t)WEL * 2;
  unsigned short* Wk = (unsigned short*)p; p += (size_t)WEL * 2;
  unsigned short* Wv = (unsigned short*)p; p += (size_t)WEL * 2;
  unsigned short* Wp = (unsigned short*)p; p += (size_t)WEL * 2;
  unsigned short* Qb = (unsigned short*)p; p += (size_t)XEL * 2;
  unsigned short* Kb = (unsigned short*)p; p += (size_t)XEL * 2;
  unsigned short* Vb = (unsigned short*)p; p += (size_t)XEL * 2;
  unsigned short* Cx = (unsigned short*)p; p += (size_t)XEL * 2;

  // attn partial buffers alias dead storage at attn time:
  //   P0 (12.58 MB f32) = out (d_out; rewritten later by gemm_out)
  //   P1 (12.58 MB f32) = Xq+Xk region (dead after gemm_qkv)
  //   L0/L1 (196 KB each) = Xv region (dead after gemm_qkv)
  float* P0 = out;
  float* P1 = (float*)Xq;
  float* L0 = (float*)Xv;
  float* L1 = (float*)Xv + 768 * 64;

  cast_all<<<(3 * X8 + 4 * W8) / 256, 256, 0, stream>>>(
      xq, xk, xv, wq, wk, wv, wp, Xq, Xk, Xv, Wq, Wk, Wv, Wp);

  gemm_qkv<<<768, 256, 0, stream>>>(
      Xq, Xk, Xv, Wq, Wk, Wv, Qb, Kb, Vb);

  attn_part<<<1536, 256, 0, stream>>>(Qb, Kb, Vb, P0, P1, L0, L1);

  attn_combine<<<768, 256, 0, stream>>>(P0, P1, L0, L1, Cx);

  gemm_out<<<512, 256, 0, stream>>>(Cx, Wp, bp, out);
}

// Round 13
// 184.736 us; speedup vs baseline: 1.8566x; 1.8566x over previous
//
#include <hip/hip_runtime.h>
#include <hip/hip_bf16.h>

// Attention: xq/xk/xv [2,2048,768] f32, W* [768,768] f32 ([out,in]), bp [768] f32.
// Pipeline: fused cast->bf16, fused QKV NT-GEMM (r17: 128x96 tiles, 768 blocks,
// 2-phase overlap + setprio), flash attention SPLIT-KV (r20): 1536 blocks
// (2 blocks per (bh,qt), each 64q x 1024kv, 32-kv tiles, 16.9 KB LDS,
// launch_bounds(256,4) -- NO hard occupancy cap; natural ~84 VGPR allocation
// gives 6 blocks/CU at runtime (r19's (256,6) cap forced accumulator spills:
// 455 MB scratch writes). 32x32 MFMA, in-register P via cvt_pk+permlane,
// overlap schedule). Blocks write UN-NORMALIZED f32 partial O + l (max-free
// softmax => partials combine exactly); combine kernel does (P0+P1)/(l0+l1)
// -> ctx bf16. Partials alias dead buffers: P0=out(f32), P1=Xq+Xk, L=Xv.
// Output NT-GEMM + bias (r17: 64x96, 512 blocks, overlap + setprio).

#define NSEQ 2048
#define CDIM 768
#define NH   12
#define HD   64
#define MTOT 4096            // B*NSEQ
#define XEL  (MTOT*CDIM)     // 3145728
#define WEL  (CDIM*CDIM)     // 589824
#define X8   (XEL/8)         // 393216
#define W8   (WEL/8)         // 73728
#define QSCALE 0.18033688011112042f   // 0.125 * log2(e); scores consumed by exp2

typedef __attribute__((ext_vector_type(8))) short bf16x8;
typedef __attribute__((ext_vector_type(4))) float floatx4;
typedef __attribute__((ext_vector_type(16))) float floatx16;
typedef __attribute__((ext_vector_type(4))) unsigned int uintx4;

// scalar f32->bf16, round-half-up (2 VALU)
static __device__ __forceinline__ unsigned short f2bf(float f) {
  union { float f; unsigned int u; } v; v.f = f;
  return (unsigned short)((v.u + 0x8000u) >> 16);
}
// packed pair f32->bf16x2, round-half-up: 2 v_add + 1 v_perm
static __device__ __forceinline__ unsigned pk2bf(float a, float b) {
  unsigned ua = __float_as_uint(a) + 0x8000u;
  unsigned ub = __float_as_uint(b) + 0x8000u;
  return __builtin_amdgcn_perm(ub, ua, 0x07060302);  // {hi16(b), hi16(a)}
}
// packed pair f32->bf16x2 via HW cvt (1 VALU, RNE): dst = {bf16(a), bf16(b)}
static __device__ __forceinline__ unsigned cvtpk(float a, float b) {
  unsigned r;
  asm("v_cvt_pk_bf16_f32 %0, %1, %2" : "=v"(r) : "v"(a), "v"(b));
  return r;
}

static __device__ __forceinline__ void lds16(const void* g, void* l) {
  __builtin_amdgcn_global_load_lds(
      (const __attribute__((address_space(1))) unsigned int*)g,
      (__attribute__((address_space(3))) unsigned int*)l, 16, 0, 0);
}

// fences for the overlap schedules
#define LGKM0_SB()  do { asm volatile("s_waitcnt lgkmcnt(0)" ::: "memory"); \
                         __builtin_amdgcn_sched_barrier(0); } while (0)
#define VMCNT0()    asm volatile("s_waitcnt vmcnt(0)" ::: "memory")
#define BARRIER()   __builtin_amdgcn_s_barrier()
#define SB0()       __builtin_amdgcn_sched_barrier(0)
#define PRIO1()     __builtin_amdgcn_s_setprio(1)
#define PRIO0()     __builtin_amdgcn_s_setprio(0)

// ---------------- fused cast f32 -> bf16 (all 7 tensors, one launch) ----------
__global__ __launch_bounds__(256) void cast_all(
    const float* __restrict__ xq, const float* __restrict__ xk,
    const float* __restrict__ xv, const float* __restrict__ wq,
    const float* __restrict__ wk, const float* __restrict__ wv,
    const float* __restrict__ wp,
    unsigned short* __restrict__ Xq, unsigned short* __restrict__ Xk,
    unsigned short* __restrict__ Xv, unsigned short* __restrict__ Wq,
    unsigned short* __restrict__ Wk, unsigned short* __restrict__ Wv,
    unsigned short* __restrict__ Wp) {
  int i = blockIdx.x * 256 + threadIdx.x;
  const float* s; unsigned short* d; int off;
  if (i < 3 * X8) {
    int t = i / X8; off = i - t * X8;
    s = (t == 0) ? xq : (t == 1) ? xk : xv;
    d = (t == 0) ? Xq : (t == 1) ? Xk : Xv;
  } else {
    int j = i - 3 * X8; int t = j / W8; off = j - t * W8;
    s = (t == 0) ? wq : (t == 1) ? wk : (t == 2) ? wv : wp;
    d = (t == 0) ? Wq : (t == 1) ? Wk : (t == 2) ? Wv : Wp;
  }
  const float4* sp = (const float4*)s + (size_t)off * 2;
  float4 a = sp[0], b = sp[1];
  uint4 o;
  o.x = pk2bf(a.x, a.y); o.y = pk2bf(a.z, a.w);
  o.z = pk2bf(b.x, b.y); o.w = pk2bf(b.z, b.w);
  *(uint4*)(d + (size_t)off * 8) = o;
}

// ---------------- fused QKV NT-GEMM: r17 version (768 blocks, 3/CU) ---------
__global__ __launch_bounds__(256) void gemm_qkv(
    const unsigned short* __restrict__ Xq, const unsigned short* __restrict__ Xk,
    const unsigned short* __restrict__ Xv, const unsigned short* __restrict__ Wq,
    const unsigned short* __restrict__ Wk, const unsigned short* __restrict__ Wv,
    unsigned short* __restrict__ Qo, unsigned short* __restrict__ Ko,
    unsigned short* __restrict__ Vo) {
  int i0 = blockIdx.x;
  int mg = i0 & 7; int t0 = i0 >> 3;       // t0 in [0,96)
  int z = t0 % 3; int u = t0 / 3;          // u in [0,32)
  int xn = u & 7, ysub = u >> 3;           // 8 n-tiles x 4 m-subtiles
  int y = mg * 4 + ysub;                   // m-tile in [0,32)
  const unsigned short* A; const unsigned short* B; int am0, bn0, RA;
  if (z == 0)      { A = Xq; B = Wq; am0 = y * 128; bn0 = xn * 96; RA = 128; }
  else if (z == 1) { A = Xk; B = Wk; am0 = y * 128; bn0 = xn * 96; RA = 128; }
  else             { A = Wv; B = Xv; am0 = xn * 96; bn0 = y * 128; RA = 96; }
  __shared__ __align__(16) unsigned short S[224 * 64];
  int tid = threadIdx.x, lane = tid & 63, wave = tid >> 6;
  int quad = lane >> 4, l15 = lane & 15, l7 = l15 & 7;

  const unsigned short* gptr[7]; int ldo[7];
#pragma unroll
  for (int i = 0; i < 7; i++) {
    int idx = i * 256 + tid;
    int row = idx >> 3, c = (idx & 7) ^ (row & 7);
    gptr[i] = (row < RA ? A + (size_t)(am0 + row) * CDIM
                        : B + (size_t)(bn0 + row - RA) * CDIM) + c * 8;
    ldo[i] = idx * 8;
  }
  floatx4 acc[12];
#pragma unroll
  for (int i = 0; i < 12; i++) acc[i] = (floatx4){0.f, 0.f, 0.f, 0.f};

  // prologue: stage k0=0
#pragma unroll
  for (int i = 0; i < 7; i++) lds16(gptr[i], &S[ldo[i]]);
  VMCNT0();
  BARRIER();

  if (z < 2) {
    int wm = (wave >> 1) * 64, wn = (wave & 1) * 48;
    for (int k0 = 0; k0 < CDIM; k0 += 64) {
      bf16x8 af[2][4], bfr[2][3];
#pragma unroll
      for (int ks = 0; ks < 2; ks++) {
        int csw = ((ks * 4 + quad) ^ l7) * 8;
#pragma unroll
        for (int i = 0; i < 4; i++)
          af[ks][i] = *(const bf16x8*)&S[(wm + i * 16 + l15) * 64 + csw];
#pragma unroll
        for (int j = 0; j < 3; j++)
          bfr[ks][j] = *(const bf16x8*)&S[(128 + wn + j * 16 + l15) * 64 + csw];
      }
      LGKM0_SB();
      BARRIER();
      if (k0 + 64 < CDIM) {
#pragma unroll
        for (int i = 0; i < 7; i++) lds16(gptr[i] + k0 + 64, &S[ldo[i]]);
      }
      SB0();
      PRIO1();
#pragma unroll
      for (int ks = 0; ks < 2; ks++)
#pragma unroll
        for (int mi = 0; mi < 4; mi++)
#pragma unroll
          for (int ni = 0; ni < 3; ni++)
            acc[mi * 3 + ni] = __builtin_amdgcn_mfma_f32_16x16x32_bf16(
                af[ks][mi], bfr[ks][ni], acc[mi * 3 + ni], 0, 0, 0);
      PRIO0();
      VMCNT0();
      BARRIER();
    }
#pragma unroll
    for (int mi = 0; mi < 4; mi++)
#pragma unroll
      for (int ni = 0; ni < 3; ni++)
#pragma unroll
        for (int r = 0; r < 4; r++) {
          int grow = am0 + wm + mi * 16 + quad * 4 + r;
          int gcol = bn0 + wn + ni * 16 + l15;
          float v = acc[mi * 3 + ni][r];
          int b = grow >> 11, nq = grow & 2047, h = gcol >> 6, dd = gcol & 63;
          if (z == 0)
            Qo[((size_t)(b * NH + h) * NSEQ + nq) * HD + dd] = f2bf(v * QSCALE);
          else
            Ko[((size_t)(b * NH + h) * NSEQ + nq) * HD + dd] = f2bf(v);
        }
  } else {
    int wm = (wave & 1) * 48, wn = (wave >> 1) * 64;
    for (int k0 = 0; k0 < CDIM; k0 += 64) {
      bf16x8 af[2][3], bfr[2][4];
#pragma unroll
      for (int ks = 0; ks < 2; ks++) {
        int csw = ((ks * 4 + quad) ^ l7) * 8;
#pragma unroll
        for (int i = 0; i < 3; i++)
          af[ks][i] = *(const bf16x8*)&S[(wm + i * 16 + l15) * 64 + csw];
#pragma unroll
        for (int j = 0; j < 4; j++)
          bfr[ks][j] = *(const bf16x8*)&S[(96 + wn + j * 16 + l15) * 64 + csw];
      }
      LGKM0_SB();
      BARRIER();
      if (k0 + 64 < CDIM) {
#pragma unroll
        for (int i = 0; i < 7; i++) lds16(gptr[i] + k0 + 64, &S[ldo[i]]);
      }
      SB0();
      PRIO1();
#pragma unroll
      for (int ks = 0; ks < 2; ks++)
#pragma unroll
        for (int mi = 0; mi < 3; mi++)
#pragma unroll
          for (int ni = 0; ni < 4; ni++)
            acc[mi * 4 + ni] = __builtin_amdgcn_mfma_f32_16x16x32_bf16(
                af[ks][mi], bfr[ks][ni], acc[mi * 4 + ni], 0, 0, 0);
      PRIO0();
      VMCNT0();
      BARRIER();
    }
#pragma unroll
    for (int mi = 0; mi < 3; mi++)
#pragma unroll
      for (int ni = 0; ni < 4; ni++)
#pragma unroll
        for (int r = 0; r < 4; r++) {
          int o = am0 + wm + mi * 16 + quad * 4 + r;
          int mgl = bn0 + wn + ni * 16 + l15;
          int b = mgl >> 11, nq = mgl & 2047;
          Vo[((size_t)b * CDIM + o) * NSEQ + nq] = f2bf(acc[mi * 4 + ni][r]);
        }
  }
}

// ---------------- flash attention r20: split-kv partials ---------------------
// Q,K: [24][2048][64] bf16 (Q pre-scaled); Vt: [24][64][2048] bf16.
// 1536 blocks x 256 thr = 4 waves: block = (bh, qt, kvh) covers 64 q x 1024 kv.
// wave = (half<<1)|qsub: 32 q x 512 kv per wave, 16 tiles of 32 kv.
// launch_bounds(256,4): no aggressive VGPR cap (r19 lesson -- (256,6) forced
// accumulator spills); natural ~84 VGPR => runtime 6 waves/SIMD occupancy.
// Per tile: 8 frag ds_read -> lgkm0+schedbar+barrier -> stage t+1 same buffer
// -> register compute (4 QK MFMA chain, 16 exp2, 8 cvt_pk, permlane, 4 PV) ->
// vmcnt0+barrier. Max-free softmax: block writes UN-NORMALIZED partial
// O (f32, [slot][64q][64d]) + l; cross-block combine is exact.
__global__ __launch_bounds__(256, 4) void attn_part(
    const unsigned short* __restrict__ Q, const unsigned short* __restrict__ K,
    const unsigned short* __restrict__ Vt,
    float* __restrict__ P0, float* __restrict__ P1,
    float* __restrict__ L0, float* __restrict__ L1) {
  int i0 = blockIdx.x;
  int xcd = i0 & 7; int t0 = i0 >> 3;      // [0,192)
  int bh = xcd * 3 + (t0 >> 6);
  int rem = t0 & 63;
  int qt = rem >> 1, kvh = rem & 1;
  int tid = threadIdx.x, lane = tid & 63, wave = tid >> 6;
  int half = wave >> 1, qsub = wave & 1;
  int l31 = lane & 31, hi = lane >> 5;
  // SM arena: [0,8KB) = K halves (2 x 32x64 bf16), [8KB,16KB) = V halves
  __shared__ __align__(16) unsigned short SM[8192];
  __shared__ float Lbuf[64];

  const unsigned short* Qg = Q + ((size_t)bh * NSEQ + qt * 64 + qsub * 32) * HD;
  const unsigned short* Kg = K + ((size_t)bh * NSEQ + kvh * 1024 + half * 512) * HD;
  const unsigned short* Vg = Vt + (size_t)bh * HD * NSEQ + kvh * 1024 + half * 512;

  // Q fragments (B-operand): lane holds Q[q=l31][d = dc*16 + hi*8 + j]
  bf16x8 qf[4];
#pragma unroll
  for (int dc = 0; dc < 4; dc++)
    qf[dc] = *(const bf16x8*)(Qg + l31 * HD + dc * 16 + hi * 8);

  // staging: each half's 128 threads stage 4KB K (32x64) + 4KB V (64x32)
  int tid2 = tid & 127;
  int kgo[2], kst[2], vgo[2], vst[2];
#pragma unroll
  for (int i = 0; i < 2; i++) {
    int idx = i * 128 + tid2;
    int Rk = idx >> 3, ck = (idx & 7) ^ (Rk & 7);
    kgo[i] = Rk * HD + ck * 8; kst[i] = idx * 8;
    int Rv = idx >> 2, cv = (idx & 3) ^ (Rv & 3);
    vgo[i] = Rv * NSEQ + cv * 8; vst[i] = idx * 8;
  }
  unsigned short* Ksh = &SM[half * 2048];
  unsigned short* Vsh = &SM[4096 + half * 2048];

  floatx16 o[2];
#pragma unroll
  for (int dt = 0; dt < 2; dt++) o[dt] = (floatx16)(0.f);
  float l_acc = 0.f;

  // prologue: stage tile 0
#pragma unroll
  for (int i = 0; i < 2; i++) {
    lds16(Kg + kgo[i], &Ksh[kst[i]]);
    lds16(Vg + vgo[i], &Vsh[vst[i]]);
  }
  VMCNT0();
  BARRIER();

  for (int t = 0; t < 16; t++) {
    // (a) fragment reads of tile t (32 kv)
    bf16x8 kf[4];
#pragma unroll
    for (int dc = 0; dc < 4; dc++) {
      int c = dc * 2 + hi;
      kf[dc] = *(const bf16x8*)&Ksh[l31 * 64 + ((c ^ (l31 & 7)) * 8)];
    }
    bf16x8 vf[2][2];
#pragma unroll
    for (int dt = 0; dt < 2; dt++)
#pragma unroll
      for (int kvs = 0; kvs < 2; kvs++) {
        int R = dt * 32 + l31, c = kvs * 2 + hi;
        vf[dt][kvs] = *(const bf16x8*)&Vsh[R * 32 + ((c ^ (R & 3)) * 8)];
      }
    // (b) readers-done fence
    LGKM0_SB();
    BARRIER();
    // (c) stage tile t+1 into the same buffer
    if (t < 15) {
      int off = (t + 1) * 32;
#pragma unroll
      for (int i = 0; i < 2; i++) {
        lds16(Kg + (size_t)off * HD + kgo[i], &Ksh[kst[i]]);
        lds16(Vg + off + vgo[i], &Vsh[vst[i]]);
      }
    }
    SB0();
    // (d) register-only compute: S^T[kv32][q32] = K Q^T
    floatx16 st = (floatx16)(0.f);
    PRIO1();
#pragma unroll
    for (int dc = 0; dc < 4; dc++)
      st = __builtin_amdgcn_mfma_f32_32x32x16_bf16(kf[dc], qf[dc], st, 0, 0, 0);
    PRIO0();
    float p[16];
#pragma unroll
    for (int r = 0; r < 16; r++) p[r] = __builtin_exp2f(st[r]);
    l_acc += ((p[0] + p[1]) + (p[2] + p[3])) + ((p[4] + p[5]) + (p[6] + p[7])) +
             (((p[8] + p[9]) + (p[10] + p[11])) + ((p[12] + p[13]) + (p[14] + p[15])));
    unsigned w[8];
#pragma unroll
    for (int i = 0; i < 8; i++) w[i] = cvtpk(p[2 * i], p[2 * i + 1]);
#pragma unroll
    for (int kvs = 0; kvs < 2; kvs++) {
      unsigned a0 = w[kvs * 4 + 0], b0 = w[kvs * 4 + 2];
      unsigned a1 = w[kvs * 4 + 1], b1 = w[kvs * 4 + 3];
      asm volatile("v_permlane32_swap_b32 %0, %1" : "+v"(a0), "+v"(b0));
      asm volatile("v_permlane32_swap_b32 %0, %1" : "+v"(a1), "+v"(b1));
      uintx4 pw; pw[0] = a0; pw[1] = a1; pw[2] = b0; pw[3] = b1;
      bf16x8 pb = *(bf16x8*)&pw;
      PRIO1();
#pragma unroll
      for (int dt = 0; dt < 2; dt++)
        o[dt] = __builtin_amdgcn_mfma_f32_32x32x16_bf16(
            vf[dt][kvs], pb, o[dt], 0, 0, 0);
      PRIO0();
    }
    // (e) stage-done fence
    VMCNT0();
    BARRIER();
  }

  // complete l across lane halves
  unsigned lu = __float_as_uint(l_acc), lv = __float_as_uint(l_acc);
  asm volatile("v_permlane32_swap_b32 %0, %1" : "+v"(lu), "+v"(lv));
  float lfull = __uint_as_float(lu) + __uint_as_float(lv);

  // in-block kv-half combine: half-1 -> LDS (SM arena, 16 KB Obuf), half-0
  // adds and writes UN-NORMALIZED partial + l to global.
  float* Obuf = (float*)&SM[0];   // 64q x 64d f32 = 16 KB
  int q = qsub * 32 + l31;
  int slot = bh * 32 + qt;
  float* Pdst = (kvh == 0) ? P0 : P1;
  float* Ldst = (kvh == 0) ? L0 : L1;
  if (half == 1) {
#pragma unroll
    for (int dt = 0; dt < 2; dt++)
#pragma unroll
      for (int rq = 0; rq < 4; rq++) {
        int ch = (dt * 8 + rq * 2 + hi) ^ (l31 & 15);
        floatx4 v4 = {o[dt][rq * 4 + 0], o[dt][rq * 4 + 1],
                      o[dt][rq * 4 + 2], o[dt][rq * 4 + 3]};
        *(floatx4*)&Obuf[q * 64 + ch * 4] = v4;
      }
    if (hi == 0) Lbuf[q] = lfull;
  }
  __syncthreads();
  if (half == 0) {
#pragma unroll
    for (int dt = 0; dt < 2; dt++)
#pragma unroll
      for (int rq = 0; rq < 4; rq++) {
        int ch = (dt * 8 + rq * 2 + hi) ^ (l31 & 15);
        floatx4 ob = *(floatx4*)&Obuf[q * 64 + ch * 4];
        floatx4 v4 = {o[dt][rq * 4 + 0] + ob[0], o[dt][rq * 4 + 1] + ob[1],
                      o[dt][rq * 4 + 2] + ob[2], o[dt][rq * 4 + 3] + ob[3]};
        *(floatx4*)&Pdst[(size_t)slot * 4096 + q * 64 + dt * 32 + rq * 8 + hi * 4] = v4;
      }
    if (hi == 0) Ldst[slot * 64 + q] = lfull + Lbuf[q];
  }
}

// ---------------- attn combine: ctx = (P0+P1) / (l0+l1) ----------------------
// 768 blocks x 256 thr; each block = one (bh,qt) slot. Thread handles 16
// contiguous f32 (one q row, 16 d's) -> 16 bf16 (32B coalesced store).
__global__ __launch_bounds__(256) void attn_combine(
    const float* __restrict__ P0, const float* __restrict__ P1,
    const float* __restrict__ L0, const float* __restrict__ L1,
    unsigned short* __restrict__ ctx) {
  int slot = blockIdx.x;
  int bh = slot >> 5, qt = slot & 31;
  int b = bh / NH, h = bh - b * NH;
  int tid = threadIdx.x;
  int e0 = tid * 16;
  int q = e0 >> 6, d0 = e0 & 63;
  float inv = 1.f / (L0[slot * 64 + q] + L1[slot * 64 + q]);
  const float4* p0 = (const float4*)(P0 + (size_t)slot * 4096 + e0);
  const float4* p1 = (const float4*)(P1 + (size_t)slot * 4096 + e0);
  unsigned short* dst =
      ctx + ((size_t)(b * NSEQ + qt * 64 + q)) * CDIM + h * HD + d0;
#pragma unroll
  for (int g = 0; g < 2; g++) {
    float4 x0 = p0[g * 2 + 0], x1 = p0[g * 2 + 1];
    float4 y0 = p1[g * 2 + 0], y1 = p1[g * 2 + 1];
    uint4 ov;
    ov.x = pk2bf((x0.x + y0.x) * inv, (x0.y + y0.y) * inv);
    ov.y = pk2bf((x0.z + y0.z) * inv, (x0.w + y0.w) * inv);
    ov.z = pk2bf((x1.x + y1.x) * inv, (x1.y + y1.y) * inv);
    ov.w = pk2bf((x1.z + y1.z) * inv, (x1.w + y1.w) * inv);
    *(uint4*)(dst + g * 8) = ov;
  }
}

// ------------- output NT-GEMM + bias, 64x96 tiles, BK=128, XCD-swizzled ------
// 2-phase overlap schedule + T5 setprio (r17 version, 512 blocks).
__global__ __launch_bounds__(256) void gemm_out(
    const unsigned short* __restrict__ A, const unsigned short* __restrict__ B,
    const float* __restrict__ bias, float* __restrict__ out) {
  int i0 = blockIdx.x;                  // 512 blocks = 2/CU
  int mg = i0 & 7; int t0 = i0 >> 3;    // t0 in [0,64)
  int n0 = (t0 & 7) * 96;
  int m0 = (mg * 8 + (t0 >> 3)) * 64;
  __shared__ __align__(16) unsigned short S[160 * 128];  // A rows 0..63, B rows 64..159
  int tid = threadIdx.x, lane = tid & 63, wave = tid >> 6;
  int quad = lane >> 4, l15 = lane & 15, l7 = l15 & 7;
  int wm = (wave >> 1) * 32, wn = (wave & 1) * 48;
  floatx4 acc[6];
#pragma unroll
  for (int i = 0; i < 6; i++) acc[i] = (floatx4){0.f, 0.f, 0.f, 0.f};

  int sro[10]; const unsigned short* sgp[10];
#pragma unroll
  for (int i = 0; i < 10; i++) {       // 160 rows x 16 chunks = 2560 = 10*256
    int idx = i * 256 + tid;
    int R = idx >> 4, c4 = idx & 15;
    int cs = (c4 & 8) | ((c4 & 7) ^ (R & 7));
    sgp[i] = ((R < 64) ? A + (size_t)(m0 + R) * CDIM
                       : B + (size_t)(n0 + R - 64) * CDIM) + cs * 8;
    sro[i] = idx * 8;
  }
  // prologue: stage k0=0
#pragma unroll
  for (int i = 0; i < 10; i++) lds16(sgp[i], &S[sro[i]]);
  VMCNT0();
  BARRIER();

  for (int k0 = 0; k0 < CDIM; k0 += 128) {
    bf16x8 af[4][2], bfr[4][3];
#pragma unroll
    for (int ks = 0; ks < 4; ks++) {
      int c = ks * 4 + quad;
      int csw = ((c & 8) | ((c & 7) ^ l7)) * 8;
#pragma unroll
      for (int i = 0; i < 2; i++)
        af[ks][i] = *(const bf16x8*)&S[(wm + i * 16 + l15) * 128 + csw];
#pragma unroll
      for (int j = 0; j < 3; j++)
        bfr[ks][j] = *(const bf16x8*)&S[(64 + wn + j * 16 + l15) * 128 + csw];
    }
    LGKM0_SB();
    BARRIER();
    if (k0 + 128 < CDIM) {
#pragma unroll
      for (int i = 0; i < 10; i++) lds16(sgp[i] + k0 + 128, &S[sro[i]]);
    }
    SB0();
    PRIO1();
#pragma unroll
    for (int ks = 0; ks < 4; ks++)
#pragma unroll
      for (int mi = 0; mi < 2; mi++)
#pragma unroll
        for (int ni = 0; ni < 3; ni++)
          acc[mi * 3 + ni] = __builtin_amdgcn_mfma_f32_16x16x32_bf16(
              af[ks][mi], bfr[ks][ni], acc[mi * 3 + ni], 0, 0, 0);
    PRIO0();
    VMCNT0();
    BARRIER();
  }
  float bv[3];
#pragma unroll
  for (int ni = 0; ni < 3; ni++) bv[ni] = bias[n0 + wn + ni * 16 + l15];
#pragma unroll
  for (int mi = 0; mi < 2; mi++)
#pragma unroll
    for (int ni = 0; ni < 3; ni++)
#pragma unroll
      for (int r = 0; r < 4; r++) {
        int grow = m0 + wm + mi * 16 + quad * 4 + r;
        int gcol = n0 + wn + ni * 16 + l15;
        out[(size_t)grow * CDIM + gcol] = acc[mi * 3 + ni][r] + bv[ni];
      }
}

extern "C" void kernel_launch(void* const* d_in, const int* in_sizes, int n_in,
                              void* d_out, int out_size, void* d_ws, size_t ws_size,
                              hipStream_t stream) {
  const float* xq = (const float*)d_in[0];
  const float* xk = (const float*)d_in[1];
  const float* xv = (const float*)d_in[2];
  const float* wq = (const float*)d_in[3];
  const float* wk = (const float*)d_in[4];
  const float* wv = (const float*)d_in[5];
  const float* wp = (const float*)d_in[6];
  const float* bp = (const float*)d_in[7];
  float* out = (float*)d_out;

  char* p = (char*)d_ws;
  unsigned short* Xq = (unsigned short*)p; p += (size_t)XEL * 2;
  unsigned short* Xk = (unsigned short*)p; p += (size_t)XEL * 2;
  unsigned short* Xv = (unsigned short*)p; p += (size_t)XEL * 2;
  unsigned short* Wq = (unsigned short*)p; p += (size_t)WEL * 2;
  unsigned short* Wk = (unsigned short*)p; p += (size_t)WEL * 2;
  unsigned short* Wv = (unsigned short*)p; p += (size_t)WEL * 2;
  unsigned short* Wp = (unsigned short*)p; p += (size_t)WEL * 2;
  unsigned short* Qb = (unsigned short*)p; p += (size_t)XEL * 2;
  unsigned short* Kb = (unsigned short*)p; p += (size_t)XEL * 2;
  unsigned short* Vb = (unsigned short*)p; p += (size_t)XEL * 2;
  unsigned short* Cx = (unsigned short*)p; p += (size_t)XEL * 2;

  // attn partial buffers alias dead storage at attn time:
  //   P0 (12.58 MB f32) = out (d_out; rewritten later by gemm_out)
  //   P1 (12.58 MB f32) = Xq+Xk region (dead after gemm_qkv)
  //   L0/L1 (196 KB each) = Xv region (dead after gemm_qkv)
  float* P0 = out;
  float* P1 = (float*)Xq;
  float* L0 = (float*)Xv;
  float* L1 = (float*)Xv + 768 * 64;

  cast_all<<<(3 * X8 + 4 * W8) / 256, 256, 0, stream>>>(
      xq, xk, xv, wq, wk, wv, wp, Xq, Xk, Xv, Wq, Wk, Wv, Wp);

  gemm_qkv<<<768, 256, 0, stream>>>(
      Xq, Xk, Xv, Wq, Wk, Wv, Qb, Kb, Vb);

  attn_part<<<1536, 256, 0, stream>>>(Qb, Kb, Vb, P0, P1, L0, L1);

  attn_combine<<<768, 256, 0, stream>>>(P0, P1, L0, L1, Cx);

  gemm_out<<<512, 256, 0, stream>>>(Cx, Wp, bp, out);
}